// Round 1
// baseline (725.076 us; speedup 1.0000x reference)
//
#include <hip/hip_runtime.h>

#define D_MODEL 4544
#define E_QKV   4672     // D + 2*64
#define E_PAD   4736     // 37*128
#define D_PAD   4608     // 36*128
#define NH      71
#define SEQ     1024
#define NB      2
#define M_ROWS  2048     // NB*SEQ

typedef __bf16 bf16_t;
typedef bf16_t bf16x8 __attribute__((ext_vector_type(8)));
typedef float f32x4 __attribute__((ext_vector_type(4)));

typedef __attribute__((address_space(1))) const void* gas_ptr;
typedef __attribute__((address_space(3))) void* las_ptr;

static __device__ __forceinline__ unsigned short f2bf(float f) {
  union { float f; unsigned u; } v; v.f = f;
  unsigned r = (v.u + 0x7fffu + ((v.u >> 16) & 1u)) >> 16;
  return (unsigned short)r;
}

// dst[rows_pad][cols] bf16 <- src[rows_src][cols] f32, pad rows zeroed. 4 elems/thread.
__global__ void convert_pad(const float* __restrict__ src, unsigned short* __restrict__ dst,
                            int rows_src, int rows_pad, int cols) {
  int idx = blockIdx.x * 256 + threadIdx.x;
  int cols4 = cols >> 2;
  int total = rows_pad * cols4;
  if (idx >= total) return;
  int row = idx / cols4;
  int c4 = (idx - row * cols4) << 2;
  ushort4 o;
  if (row < rows_src) {
    const float4 v = *(const float4*)(src + (size_t)row * cols + c4);
    o.x = f2bf(v.x); o.y = f2bf(v.y); o.z = f2bf(v.z); o.w = f2bf(v.w);
  } else {
    o.x = 0; o.y = 0; o.z = 0; o.w = 0;
  }
  *(ushort4*)(dst + (size_t)row * cols + c4) = o;
}

// C[M][ldc] (f32) = A[M][K] * B[Npad][K]^T   (bf16 inputs, fp32 accum)
// 128x128 tile, BK=64, 4 waves (2x2), 16x16x32 MFMA, global_load_lds staging.
__global__ __launch_bounds__(256) void gemm_bt(
    const unsigned short* __restrict__ A,
    const unsigned short* __restrict__ B,
    float* __restrict__ C,
    int M, int K, int ldc, int Nact) {
  __shared__ __align__(16) unsigned short lA[128 * 64];
  __shared__ __align__(16) unsigned short lB[128 * 64];
  const int tid = threadIdx.x;
  const int wave = tid >> 6;
  const int lane = tid & 63;
  const int g = lane >> 4, c = lane & 15;
  const int row0 = blockIdx.x * 128;
  const int col0 = blockIdx.y * 128;
  const int wr = wave >> 1, wc = wave & 1;

  f32x4 acc[4][4] = {};

  for (int k0 = 0; k0 < K; k0 += 64) {
#pragma unroll
    for (int i = 0; i < 4; ++i) {
      int ch = i * 256 + tid;          // chunk id 0..1023, 8 bf16 each
      int r = ch >> 3;
      int cc = (ch & 7) << 3;
      const unsigned short* ga = A + (size_t)(row0 + r) * K + k0 + cc;
      const unsigned short* gb = B + (size_t)(col0 + r) * K + k0 + cc;
      int ldsoff = (i * 256 + wave * 64) << 3;   // elements (wave-uniform)
      __builtin_amdgcn_global_load_lds((gas_ptr)ga, (las_ptr)(lA + ldsoff), 16, 0, 0);
      __builtin_amdgcn_global_load_lds((gas_ptr)gb, (las_ptr)(lB + ldsoff), 16, 0, 0);
    }
    __syncthreads();
#pragma unroll
    for (int kk = 0; kk < 64; kk += 32) {
      bf16x8 af[4], bfr[4];
#pragma unroll
      for (int m = 0; m < 4; ++m)
        af[m] = *(const bf16x8*)&lA[(wr * 64 + m * 16 + c) * 64 + kk + g * 8];
#pragma unroll
      for (int n = 0; n < 4; ++n)
        bfr[n] = *(const bf16x8*)&lB[(wc * 64 + n * 16 + c) * 64 + kk + g * 8];
#pragma unroll
      for (int m = 0; m < 4; ++m)
#pragma unroll
        for (int n = 0; n < 4; ++n)
          acc[m][n] = __builtin_amdgcn_mfma_f32_16x16x32_bf16(af[m], bfr[n], acc[m][n], 0, 0, 0);
    }
    __syncthreads();
  }

#pragma unroll
  for (int m = 0; m < 4; ++m) {
#pragma unroll
    for (int n = 0; n < 4; ++n) {
      int col = col0 + wc * 64 + n * 16 + c;
      if (col < Nact) {
#pragma unroll
        for (int r = 0; r < 4; ++r) {
          int row = row0 + wr * 64 + m * 16 + g * 4 + r;
          C[(size_t)row * ldc + col] = acc[m][n][r];
        }
      }
    }
  }
}

// fused[n][l][E_PAD] f32 -> Qb [n][h][l][64] bf16 (RoPE, *0.125), Kb [n][l][64] (RoPE),
// VTb [n][64][SEQ] (transposed V, no RoPE)
__global__ void rope_extract(const float* __restrict__ fused,
                             unsigned short* __restrict__ Qb,
                             unsigned short* __restrict__ Kb,
                             unsigned short* __restrict__ VTb) {
  int idx = blockIdx.x * 256 + threadIdx.x;
  const int total = NB * SEQ * 73 * 64;
  if (idx >= total) return;
  int d = idx & 63;
  int t = idx >> 6;
  int h = t % 73;  t /= 73;
  int l = t & (SEQ - 1);
  int n = t >> 10;
  const float* frow = fused + ((size_t)(n * SEQ + l)) * E_PAD + h * 64;
  float x = frow[d];
  if (h == 72) {  // V head, transposed store
    VTb[((size_t)(n * 64 + d)) * SEQ + l] = f2bf(x);
    return;
  }
  int dh = d & 31;
  float inv = __expf(-(float)dh * (9.210340371976184f / 32.0f));  // 10000^(-dh/32)
  float ang = (float)l * inv;
  float sn, cs;
  __sincosf(ang, &sn, &cs);
  float xr = frow[(d < 32) ? d + 32 : d - 32];
  float rh = (d < 32) ? -xr : xr;
  float out = x * cs + rh * sn;
  if (h == 71) {
    Kb[((size_t)(n * SEQ + l)) * 64 + d] = f2bf(out);
  } else {
    Qb[(((size_t)(n * NH + h)) * SEQ + l) * 64 + d] = f2bf(out * 0.125f);
  }
}

// Flash-style causal MQA. Block = (qtile of 64 rows, head, batch); 4 waves x 16 q-rows.
// k-tiles of 32 keys. S via mfma(Q, K^T); P through per-wave LDS; PV via mfma(P, V).
__global__ __launch_bounds__(256) void attn_kernel(
    const unsigned short* __restrict__ Qb,
    const unsigned short* __restrict__ Kb,
    const unsigned short* __restrict__ VTb,
    unsigned short* __restrict__ attnb) {
  const int qt = blockIdx.x, h = blockIdx.y, n = blockIdx.z;
  const int wave = threadIdx.x >> 6, lane = threadIdx.x & 63;
  const int g = lane >> 4, c = lane & 15;
  const int qrow0 = qt * 64 + wave * 16;

  __shared__ __align__(16) unsigned short pl[4][16 * 32];
  unsigned short* myp = pl[wave];

  const unsigned short* qbase = Qb + (((size_t)(n * NH + h)) * SEQ + qrow0) * 64;
  const unsigned short* kbase = Kb + (size_t)n * SEQ * 64;
  const unsigned short* vtbase = VTb + (size_t)n * 64 * SEQ;

  bf16x8 qf0 = *(const bf16x8*)&qbase[c * 64 + g * 8];
  bf16x8 qf1 = *(const bf16x8*)&qbase[c * 64 + 32 + g * 8];

  f32x4 o[4] = {};
  float m_run[4], l_run[4];
#pragma unroll
  for (int r = 0; r < 4; ++r) { m_run[r] = -1e30f; l_run[r] = 0.f; }

  const int nk = qrow0 + 16;  // causal: keys 0..qrow0+15
  for (int kt = 0; kt < nk; kt += 32) {
    f32x4 s0 = {0.f, 0.f, 0.f, 0.f}, s1 = {0.f, 0.f, 0.f, 0.f};
    {
      bf16x8 ka = *(const bf16x8*)&kbase[(kt + c) * 64 + g * 8];
      bf16x8 kb2 = *(const bf16x8*)&kbase[(kt + c) * 64 + 32 + g * 8];
      s0 = __builtin_amdgcn_mfma_f32_16x16x32_bf16(qf0, ka, s0, 0, 0, 0);
      s0 = __builtin_amdgcn_mfma_f32_16x16x32_bf16(qf1, kb2, s0, 0, 0, 0);
      bf16x8 kc = *(const bf16x8*)&kbase[(kt + 16 + c) * 64 + g * 8];
      bf16x8 kd = *(const bf16x8*)&kbase[(kt + 16 + c) * 64 + 32 + g * 8];
      s1 = __builtin_amdgcn_mfma_f32_16x16x32_bf16(qf0, kc, s1, 0, 0, 0);
      s1 = __builtin_amdgcn_mfma_f32_16x16x32_bf16(qf1, kd, s1, 0, 0, 0);
    }
    float al[4];
#pragma unroll
    for (int r = 0; r < 4; ++r) {
      const int qr = qrow0 + g * 4 + r;
      float v0 = (kt + c > qr) ? -1e30f : s0[r];
      float v1 = (kt + 16 + c > qr) ? -1e30f : s1[r];
      float mx = fmaxf(v0, v1);
#pragma unroll
      for (int off = 1; off < 16; off <<= 1)
        mx = fmaxf(mx, __shfl_xor(mx, off));
      float mn = fmaxf(m_run[r], mx);
      float a = __expf(m_run[r] - mn);
      float p0 = __expf(v0 - mn);
      float p1 = __expf(v1 - mn);
      float ps = p0 + p1;
#pragma unroll
      for (int off = 1; off < 16; off <<= 1)
        ps += __shfl_xor(ps, off);
      l_run[r] = l_run[r] * a + ps;
      m_run[r] = mn;
      al[r] = a;
      myp[(g * 4 + r) * 32 + c] = f2bf(p0);
      myp[(g * 4 + r) * 32 + 16 + c] = f2bf(p1);
    }
#pragma unroll
    for (int dc = 0; dc < 4; ++dc)
#pragma unroll
      for (int r = 0; r < 4; ++r) o[dc][r] *= al[r];
    bf16x8 pa = *(const bf16x8*)&myp[c * 32 + g * 8];
#pragma unroll
    for (int dc = 0; dc < 4; ++dc) {
      bf16x8 vf = *(const bf16x8*)&vtbase[(size_t)(dc * 16 + c) * SEQ + kt + g * 8];
      o[dc] = __builtin_amdgcn_mfma_f32_16x16x32_bf16(pa, vf, o[dc], 0, 0, 0);
    }
  }

  const int colbase = h * 64;
#pragma unroll
  for (int dc = 0; dc < 4; ++dc) {
#pragma unroll
    for (int r = 0; r < 4; ++r) {
      float v = o[dc][r] / l_run[r];
      int row = n * SEQ + qrow0 + g * 4 + r;
      attnb[(size_t)row * D_MODEL + colbase + dc * 16 + c] = f2bf(v);
    }
  }
}

extern "C" void kernel_launch(void* const* d_in, const int* in_sizes, int n_in,
                              void* d_out, int out_size, void* d_ws, size_t ws_size,
                              hipStream_t stream) {
  const float* hs = (const float*)d_in[0];
  const float* wqkv = (const float*)d_in[1];
  const float* wdense = (const float*)d_in[2];
  float* out = (float*)d_out;
  char* ws = (char*)d_ws;

  // ws layout (bytes)
  unsigned short* hsb   = (unsigned short*)(ws + 0);            // 2048*4544*2  = 18,612,224
  unsigned short* wqkvb = (unsigned short*)(ws + 18612224);     // 4736*4544*2  = 43,044,864
  unsigned short* wdb   = (unsigned short*)(ws + 61657088);     // 4608*4544*2  = 41,881,600
  float*          fused = (float*)(ws + 103538688);             // 2048*4736*4  = 38,797,312
  unsigned short* qb    = (unsigned short*)(ws + 142336000);    // 2*71*1024*64*2 = 18,612,224
  unsigned short* kb    = (unsigned short*)(ws + 160948224);    // 2*1024*64*2  = 262,144
  unsigned short* vtb   = (unsigned short*)(ws + 161210368);    // 2*64*1024*2  = 262,144
  unsigned short* attnb = (unsigned short*)(ws + 161472512);    // 2048*4544*2  = 18,612,224
  // total: 180,084,736 bytes

  {
    int total = M_ROWS * (D_MODEL / 4);
    convert_pad<<<(total + 255) / 256, 256, 0, stream>>>(hs, hsb, M_ROWS, M_ROWS, D_MODEL);
  }
  {
    int total = E_PAD * (D_MODEL / 4);
    convert_pad<<<(total + 255) / 256, 256, 0, stream>>>(wqkv, wqkvb, E_QKV, E_PAD, D_MODEL);
  }
  {
    int total = D_PAD * (D_MODEL / 4);
    convert_pad<<<(total + 255) / 256, 256, 0, stream>>>(wdense, wdb, D_MODEL, D_PAD, D_MODEL);
  }
  gemm_bt<<<dim3(M_ROWS / 128, E_PAD / 128), 256, 0, stream>>>(hsb, wqkvb, fused,
                                                               M_ROWS, D_MODEL, E_PAD, E_PAD);
  {
    int total = NB * SEQ * 73 * 64;
    rope_extract<<<(total + 255) / 256, 256, 0, stream>>>(fused, qb, kb, vtb);
  }
  attn_kernel<<<dim3(SEQ / 64, NH, NB), 256, 0, stream>>>(qb, kb, vtb, attnb);
  gemm_bt<<<dim3(M_ROWS / 128, D_PAD / 128), 256, 0, stream>>>(attnb, wdb, out,
                                                               M_ROWS, D_MODEL, D_MODEL, D_MODEL);
}

// Round 2
// 623.859 us; speedup vs baseline: 1.1622x; 1.1622x over previous
//
#include <hip/hip_runtime.h>

#define D_MODEL 4544
#define E_QKV   4672     // D + 2*64
#define E_PAD   4736     // 37*128
#define D_PAD   4608     // 36*128
#define NH      71
#define SEQ     1024
#define NB      2
#define M_ROWS  2048     // NB*SEQ

typedef __bf16 bf16_t;
typedef bf16_t bf16x8 __attribute__((ext_vector_type(8)));
typedef float f32x4 __attribute__((ext_vector_type(4)));
typedef float f32x16 __attribute__((ext_vector_type(16)));
typedef unsigned u32x4 __attribute__((ext_vector_type(4)));

typedef __attribute__((address_space(1))) const void* gas_ptr;
typedef __attribute__((address_space(3))) void* las_ptr;

static __device__ __forceinline__ unsigned short f2bf(float f) {
  union { float f; unsigned u; } v; v.f = f;
  unsigned r = (v.u + 0x7fffu + ((v.u >> 16) & 1u)) >> 16;
  return (unsigned short)r;
}

static __device__ __forceinline__ unsigned cvtpk_bf16(float lo, float hi) {
  unsigned r;
  asm("v_cvt_pk_bf16_f32 %0, %1, %2" : "=v"(r) : "v"(lo), "v"(hi));
  return r;
}

// dst[rows_pad][cols] bf16 <- src[rows_src][cols] f32, pad rows zeroed. 4 elems/thread.
__global__ void convert_pad(const float* __restrict__ src, unsigned short* __restrict__ dst,
                            int rows_src, int rows_pad, int cols) {
  int idx = blockIdx.x * 256 + threadIdx.x;
  int cols4 = cols >> 2;
  int total = rows_pad * cols4;
  if (idx >= total) return;
  int row = idx / cols4;
  int c4 = (idx - row * cols4) << 2;
  ushort4 o;
  if (row < rows_src) {
    const float4 v = *(const float4*)(src + (size_t)row * cols + c4);
    o.x = f2bf(v.x); o.y = f2bf(v.y); o.z = f2bf(v.z); o.w = f2bf(v.w);
  } else {
    o.x = 0; o.y = 0; o.z = 0; o.w = 0;
  }
  *(ushort4*)(dst + (size_t)row * cols + c4) = o;
}

// C[M][ldc] (f32) = A[M][K] * B[Npad][K]^T   (bf16 inputs, fp32 accum)
__global__ __launch_bounds__(256) void gemm_bt(
    const unsigned short* __restrict__ A,
    const unsigned short* __restrict__ B,
    float* __restrict__ C,
    int M, int K, int ldc, int Nact) {
  __shared__ __align__(16) unsigned short lA[128 * 64];
  __shared__ __align__(16) unsigned short lB[128 * 64];
  const int tid = threadIdx.x;
  const int wave = tid >> 6;
  const int lane = tid & 63;
  const int g = lane >> 4, c = lane & 15;
  const int row0 = blockIdx.x * 128;
  const int col0 = blockIdx.y * 128;
  const int wr = wave >> 1, wc = wave & 1;

  f32x4 acc[4][4] = {};

  for (int k0 = 0; k0 < K; k0 += 64) {
#pragma unroll
    for (int i = 0; i < 4; ++i) {
      int ch = i * 256 + tid;
      int r = ch >> 3;
      int cc = (ch & 7) << 3;
      const unsigned short* ga = A + (size_t)(row0 + r) * K + k0 + cc;
      const unsigned short* gb = B + (size_t)(col0 + r) * K + k0 + cc;
      int ldsoff = (i * 256 + wave * 64) << 3;
      __builtin_amdgcn_global_load_lds((gas_ptr)ga, (las_ptr)(lA + ldsoff), 16, 0, 0);
      __builtin_amdgcn_global_load_lds((gas_ptr)gb, (las_ptr)(lB + ldsoff), 16, 0, 0);
    }
    __syncthreads();
#pragma unroll
    for (int kk = 0; kk < 64; kk += 32) {
      bf16x8 af[4], bfr[4];
#pragma unroll
      for (int m = 0; m < 4; ++m)
        af[m] = *(const bf16x8*)&lA[(wr * 64 + m * 16 + c) * 64 + kk + g * 8];
#pragma unroll
      for (int n = 0; n < 4; ++n)
        bfr[n] = *(const bf16x8*)&lB[(wc * 64 + n * 16 + c) * 64 + kk + g * 8];
#pragma unroll
      for (int m = 0; m < 4; ++m)
#pragma unroll
        for (int n = 0; n < 4; ++n)
          acc[m][n] = __builtin_amdgcn_mfma_f32_16x16x32_bf16(af[m], bfr[n], acc[m][n], 0, 0, 0);
    }
    __syncthreads();
  }

#pragma unroll
  for (int m = 0; m < 4; ++m) {
#pragma unroll
    for (int n = 0; n < 4; ++n) {
      int col = col0 + wc * 64 + n * 16 + c;
      if (col < Nact) {
#pragma unroll
        for (int r = 0; r < 4; ++r) {
          int row = row0 + wr * 64 + m * 16 + g * 4 + r;
          C[(size_t)row * ldc + col] = acc[m][n][r];
        }
      }
    }
  }
}

// fused[n][l][E_PAD] f32 -> Qb [n][h][l][64] bf16 (RoPE, *0.125), Kb [n][l][64] (RoPE),
// VTb [n][64][SEQ] (transposed V, no RoPE)
__global__ void rope_extract(const float* __restrict__ fused,
                             unsigned short* __restrict__ Qb,
                             unsigned short* __restrict__ Kb,
                             unsigned short* __restrict__ VTb) {
  int idx = blockIdx.x * 256 + threadIdx.x;
  const int total = NB * SEQ * 73 * 64;
  if (idx >= total) return;
  int d = idx & 63;
  int t = idx >> 6;
  int h = t % 73;  t /= 73;
  int l = t & (SEQ - 1);
  int n = t >> 10;
  const float* frow = fused + ((size_t)(n * SEQ + l)) * E_PAD + h * 64;
  float x = frow[d];
  if (h == 72) {  // V head, transposed store
    VTb[((size_t)(n * 64 + d)) * SEQ + l] = f2bf(x);
    return;
  }
  int dh = d & 31;
  float inv = __expf(-(float)dh * (9.210340371976184f / 32.0f));  // 10000^(-dh/32)
  float ang = (float)l * inv;
  float sn, cs;
  __sincosf(ang, &sn, &cs);
  float xr = frow[(d < 32) ? d + 32 : d - 32];
  float rh = (d < 32) ? -xr : xr;
  float out = x * cs + rh * sn;
  if (h == 71) {
    Kb[((size_t)(n * SEQ + l)) * 64 + d] = f2bf(out);
  } else {
    Qb[(((size_t)(n * NH + h)) * SEQ + l) * 64 + d] = f2bf(out * 0.125f);
  }
}

// Swapped-QK^T flash MQA. Wave owns 32 q-rows (q = qrow0 + lane&31); KVBLK=64.
// S = mfma32(K, Q) -> P[key][q] lane-local in 2x f32x16; softmax per-lane (1 shfl);
// P->bf16 via cvt_pk + cross-half shfl (T12 layout); PV = mfma32(V^T, P).
__global__ __launch_bounds__(128) void attn_kernel(
    const unsigned short* __restrict__ Qb,
    const unsigned short* __restrict__ Kb,
    const unsigned short* __restrict__ VTb,
    unsigned short* __restrict__ attnb) {
  const int qt = 15 - blockIdx.x;   // heavy blocks first
  const int h = blockIdx.y, n = blockIdx.z;
  const int wave = threadIdx.x >> 6, lane = threadIdx.x & 63;
  const int c = lane & 31, hi = lane >> 5;
  const int qrow0 = qt * 64 + wave * 32;
  const int q = qrow0 + c;

  const unsigned short* qbase = Qb + (((size_t)(n * NH + h)) * SEQ + qrow0) * 64;
  const unsigned short* kbase = Kb + (size_t)n * SEQ * 64;
  const unsigned short* vtbase = VTb + (size_t)n * 64 * SEQ;

  bf16x8 qf[4];
#pragma unroll
  for (int cc = 0; cc < 4; ++cc)
    qf[cc] = *(const bf16x8*)&qbase[c * 64 + cc * 16 + hi * 8];

  f32x16 o0 = {}, o1 = {};
  float m_run = -1e30f, l_run = 0.f;

  for (int kt = 0; kt < qrow0 + 32; kt += 64) {
    // ---- S = K * Q^T (swapped): S[key][q], key lane-local ----
    f32x16 s0 = {}, s1 = {};
#pragma unroll
    for (int cc = 0; cc < 4; ++cc) {
      bf16x8 k0 = *(const bf16x8*)&kbase[(size_t)(kt + c) * 64 + cc * 16 + hi * 8];
      bf16x8 k1 = *(const bf16x8*)&kbase[(size_t)(kt + 32 + c) * 64 + cc * 16 + hi * 8];
      s0 = __builtin_amdgcn_mfma_f32_32x32x16_bf16(k0, qf[cc], s0, 0, 0, 0);
      s1 = __builtin_amdgcn_mfma_f32_32x32x16_bf16(k1, qf[cc], s1, 0, 0, 0);
    }
    if (kt + 63 > qrow0) {  // causal mask needed on this tile
#pragma unroll
      for (int r = 0; r < 16; ++r) {
        const int key0 = kt + (r & 3) + 8 * (r >> 2) + 4 * hi;
        s0[r] = (key0 > q) ? -1e30f : s0[r];
        s1[r] = (key0 + 32 > q) ? -1e30f : s1[r];
      }
    }
    // ---- online softmax, per-lane (q fixed per lane) ----
    float t[16];
#pragma unroll
    for (int r = 0; r < 16; ++r) t[r] = fmaxf(s0[r], s1[r]);
#pragma unroll
    for (int st = 8; st > 0; st >>= 1)
#pragma unroll
      for (int r = 0; r < 8; ++r) if (r < st) t[r] = fmaxf(t[r], t[r + st]);
    float mx = fmaxf(t[0], __shfl_xor(t[0], 32));
    const float mnew = fmaxf(m_run, mx);
    const float aa = __expf(m_run - mnew);
#pragma unroll
    for (int r = 0; r < 16; ++r) {
      s0[r] = __expf(s0[r] - mnew);
      s1[r] = __expf(s1[r] - mnew);
    }
    float ps = 0.f;
#pragma unroll
    for (int r = 0; r < 16; ++r) ps += s0[r] + s1[r];
    ps += __shfl_xor(ps, 32);
    l_run = l_run * aa + ps;
    m_run = mnew;
#pragma unroll
    for (int r = 0; r < 16; ++r) { o0[r] *= aa; o1[r] *= aa; }

    // ---- P (f32, [key][q]) -> bf16 B-fragments for PV, in-register ----
    // chunk cg covers keys kt+16*cg .. +15; frag word w holds keys 8*hi+2w,+1 (local k)
#pragma unroll
    for (int half = 0; half < 2; ++half) {
#pragma unroll
      for (int ccl = 0; ccl < 2; ++ccl) {
        const int cg = half * 2 + ccl;
        unsigned a0, a1, b0, b1;
        if (half == 0) {
          a0 = cvtpk_bf16(s0[8 * ccl + 0], s0[8 * ccl + 1]);
          a1 = cvtpk_bf16(s0[8 * ccl + 2], s0[8 * ccl + 3]);
          b0 = cvtpk_bf16(s0[8 * ccl + 4], s0[8 * ccl + 5]);
          b1 = cvtpk_bf16(s0[8 * ccl + 6], s0[8 * ccl + 7]);
        } else {
          a0 = cvtpk_bf16(s1[8 * ccl + 0], s1[8 * ccl + 1]);
          a1 = cvtpk_bf16(s1[8 * ccl + 2], s1[8 * ccl + 3]);
          b0 = cvtpk_bf16(s1[8 * ccl + 4], s1[8 * ccl + 5]);
          b1 = cvtpk_bf16(s1[8 * ccl + 6], s1[8 * ccl + 7]);
        }
        // cross-half exchange: slot w (w=0,1) = hi ? partner(b_w) : a_w
        //                      slot w+2      = hi ? b_w : partner(a_w)
        unsigned xa0 = __shfl_xor(a0, 32), xa1 = __shfl_xor(a1, 32);
        unsigned xb0 = __shfl_xor(b0, 32), xb1 = __shfl_xor(b1, 32);
        u32x4 fw;
        fw[0] = hi ? xb0 : a0;
        fw[1] = hi ? xb1 : a1;
        fw[2] = hi ? b0 : xa0;
        fw[3] = hi ? b1 : xa1;
        union { u32x4 u; bf16x8 b; } pf; pf.u = fw;
        bf16x8 v0 = *(const bf16x8*)&vtbase[(size_t)c * SEQ + kt + cg * 16 + hi * 8];
        bf16x8 v1 = *(const bf16x8*)&vtbase[(size_t)(32 + c) * SEQ + kt + cg * 16 + hi * 8];
        o0 = __builtin_amdgcn_mfma_f32_32x32x16_bf16(v0, pf.b, o0, 0, 0, 0);
        o1 = __builtin_amdgcn_mfma_f32_32x32x16_bf16(v1, pf.b, o1, 0, 0, 0);
      }
    }
  }

  const float inv = 1.0f / l_run;
  const size_t rowoff = (size_t)(n * SEQ + q) * D_MODEL + h * 64;
#pragma unroll
  for (int rr = 0; rr < 4; ++rr) {
    ushort4 w0, w1;
    w0.x = f2bf(o0[4 * rr + 0] * inv); w0.y = f2bf(o0[4 * rr + 1] * inv);
    w0.z = f2bf(o0[4 * rr + 2] * inv); w0.w = f2bf(o0[4 * rr + 3] * inv);
    w1.x = f2bf(o1[4 * rr + 0] * inv); w1.y = f2bf(o1[4 * rr + 1] * inv);
    w1.z = f2bf(o1[4 * rr + 2] * inv); w1.w = f2bf(o1[4 * rr + 3] * inv);
    *(ushort4*)&attnb[rowoff + 8 * rr + 4 * hi] = w0;
    *(ushort4*)&attnb[rowoff + 32 + 8 * rr + 4 * hi] = w1;
  }
}

extern "C" void kernel_launch(void* const* d_in, const int* in_sizes, int n_in,
                              void* d_out, int out_size, void* d_ws, size_t ws_size,
                              hipStream_t stream) {
  const float* hs = (const float*)d_in[0];
  const float* wqkv = (const float*)d_in[1];
  const float* wdense = (const float*)d_in[2];
  float* out = (float*)d_out;
  char* ws = (char*)d_ws;

  unsigned short* hsb   = (unsigned short*)(ws + 0);
  unsigned short* wqkvb = (unsigned short*)(ws + 18612224);
  unsigned short* wdb   = (unsigned short*)(ws + 61657088);
  float*          fused = (float*)(ws + 103538688);
  unsigned short* qb    = (unsigned short*)(ws + 142336000);
  unsigned short* kb    = (unsigned short*)(ws + 160948224);
  unsigned short* vtb   = (unsigned short*)(ws + 161210368);
  unsigned short* attnb = (unsigned short*)(ws + 161472512);

  {
    int total = M_ROWS * (D_MODEL / 4);
    convert_pad<<<(total + 255) / 256, 256, 0, stream>>>(hs, hsb, M_ROWS, M_ROWS, D_MODEL);
  }
  {
    int total = E_PAD * (D_MODEL / 4);
    convert_pad<<<(total + 255) / 256, 256, 0, stream>>>(wqkv, wqkvb, E_QKV, E_PAD, D_MODEL);
  }
  {
    int total = D_PAD * (D_MODEL / 4);
    convert_pad<<<(total + 255) / 256, 256, 0, stream>>>(wdense, wdb, D_MODEL, D_PAD, D_MODEL);
  }
  gemm_bt<<<dim3(M_ROWS / 128, E_PAD / 128), 256, 0, stream>>>(hsb, wqkvb, fused,
                                                               M_ROWS, D_MODEL, E_PAD, E_PAD);
  {
    int total = NB * SEQ * 73 * 64;
    rope_extract<<<(total + 255) / 256, 256, 0, stream>>>(fused, qb, kb, vtb);
  }
  attn_kernel<<<dim3(16, NH, NB), 128, 0, stream>>>(qb, kb, vtb, attnb);
  gemm_bt<<<dim3(M_ROWS / 128, D_PAD / 128), 256, 0, stream>>>(attnb, wdb, out,
                                                               M_ROWS, D_MODEL, D_MODEL, D_MODEL);
}

// Round 3
// 484.245 us; speedup vs baseline: 1.4973x; 1.2883x over previous
//
#include <hip/hip_runtime.h>

#define D_MODEL 4544
#define E_QKV   4672     // D + 2*64
#define E_STR   4736     // fused row stride (37*128)
#define E_PAD2  4864     // QKV weight rows padded (19*256)
#define D_PAD   4608     // dense weight rows padded (18*256)
#define NH      71
#define SEQ     1024
#define NB      2
#define M_ROWS  2048     // NB*SEQ

typedef __bf16 bf16_t;
typedef bf16_t bf16x8 __attribute__((ext_vector_type(8)));
typedef float f32x4 __attribute__((ext_vector_type(4)));
typedef float f32x16 __attribute__((ext_vector_type(16)));
typedef unsigned u32x4 __attribute__((ext_vector_type(4)));

typedef __attribute__((address_space(1))) const void* gas_ptr;
typedef __attribute__((address_space(3))) void* las_ptr;

static __device__ __forceinline__ unsigned short f2bf(float f) {
  union { float f; unsigned u; } v; v.f = f;
  unsigned r = (v.u + 0x7fffu + ((v.u >> 16) & 1u)) >> 16;
  return (unsigned short)r;
}

static __device__ __forceinline__ unsigned cvtpk_bf16(float lo, float hi) {
  unsigned r;
  asm("v_cvt_pk_bf16_f32 %0, %1, %2" : "=v"(r) : "v"(lo), "v"(hi));
  return r;
}

// dst[rows_pad][cols] bf16 <- src[rows_src][cols] f32, pad rows zeroed.
__global__ void convert_pad(const float* __restrict__ src, unsigned short* __restrict__ dst,
                            int rows_src, int rows_pad, int cols) {
  int idx = blockIdx.x * 256 + threadIdx.x;
  int cols4 = cols >> 2;
  int total = rows_pad * cols4;
  if (idx >= total) return;
  int row = idx / cols4;
  int c4 = (idx - row * cols4) << 2;
  ushort4 o;
  if (row < rows_src) {
    const float4 v = *(const float4*)(src + (size_t)row * cols + c4);
    o.x = f2bf(v.x); o.y = f2bf(v.y); o.z = f2bf(v.z); o.w = f2bf(v.w);
  } else {
    o.x = 0; o.y = 0; o.z = 0; o.w = 0;
  }
  *(ushort4*)(dst + (size_t)row * cols + c4) = o;
}

// ---------------- 256x256 8-phase GEMM (C = A * B^T) ----------------
// A[M][K], B[Npad][K] bf16; C[M][ldc] f32. BK=64, 8 waves (2m x 4n).
// LDS: 2 bufs x {A,B} x {k0,k1} half-tiles of [256][32] bf16 (16KB each) = 128KB.
// K-split halves give conflict-free contiguous ds_read_b128 / global_load_lds.

#define REGION(b_, op_, kh_) (((((b_)*2+(op_))*2)+(kh_)) << 13)

#define STAGE(b_, op_, kh_, kt_) do {                                          \
  const unsigned short* _src = (op_) ? B : A;                                  \
  const size_t _rb = (op_) ? bCol : bRow;                                      \
  _Pragma("unroll")                                                            \
  for (int _ld = 0; _ld < 2; ++_ld) {                                          \
    int _ch = _ld * 512 + tid;                                                 \
    const unsigned short* _ga = _src + (_rb + (_ch >> 2)) * K                  \
                                + (kt_) * 64 + (kh_) * 32 + ((_ch & 3) << 3);  \
    __builtin_amdgcn_global_load_lds((gas_ptr)_ga,                             \
        (las_ptr)(lds + REGION(b_, op_, kh_) + ((_ld * 512 + wave * 64) << 3)),\
        16, 0, 0);                                                             \
  }                                                                            \
} while (0)

#define LDA4(b_, kh_, mh_) do {                                                \
  const unsigned short* _ab = lds + REGION(b_, 0, kh_);                        \
  _Pragma("unroll")                                                            \
  for (int _mm = 0; _mm < 4; ++_mm)                                            \
    a[_mm] = *(const bf16x8*)&_ab[(wm * 128 + (mh_) * 64 + _mm * 16 + c) * 32 + g * 8]; \
} while (0)

#define LDB4(b_, kh_) do {                                                     \
  const unsigned short* _bp = lds + REGION(b_, 1, kh_);                        \
  _Pragma("unroll")                                                            \
  for (int _n = 0; _n < 4; ++_n)                                               \
    bv[_n] = *(const bf16x8*)&_bp[(wn * 64 + _n * 16 + c) * 32 + g * 8];       \
} while (0)

#define MFMA16(mh_) do {                                                       \
  _Pragma("unroll")                                                            \
  for (int _mm = 0; _mm < 4; ++_mm)                                            \
    _Pragma("unroll")                                                          \
    for (int _n = 0; _n < 4; ++_n)                                             \
      acc[(mh_) * 4 + _mm][_n] = __builtin_amdgcn_mfma_f32_16x16x32_bf16(      \
          a[_mm], bv[_n], acc[(mh_) * 4 + _mm][_n], 0, 0, 0);                  \
} while (0)

__global__ __launch_bounds__(512, 2) void gemm256(
    const unsigned short* __restrict__ A,
    const unsigned short* __restrict__ B,
    float* __restrict__ C,
    int K, int Ntiles, int ldc, int Nact) {
  __shared__ __align__(16) unsigned short lds[65536];   // 128 KiB
  const int tid = threadIdx.x;
  const int wave = tid >> 6, lane = tid & 63;
  const int g = lane >> 4, c = lane & 15;
  const int wm = wave >> 2, wn = wave & 3;
  // XCD swizzle (gridDim.x % 8 == 0): each XCD gets a contiguous chunk.
  const int nwg = gridDim.x;
  const int swz = (blockIdx.x & 7) * (nwg >> 3) + (blockIdx.x >> 3);
  const int bm = swz / Ntiles, bn = swz - bm * Ntiles;
  const size_t bRow = (size_t)bm * 256, bCol = (size_t)bn * 256;
  const int NT = K >> 6;

  f32x4 acc[8][4] = {};

  // prologue: tile0 all 4 half-tiles, tile1 {B-k0, A-k0, B-k1}
  STAGE(0, 0, 0, 0); STAGE(0, 1, 0, 0); STAGE(0, 0, 1, 0); STAGE(0, 1, 1, 0);
  STAGE(1, 1, 0, 1); STAGE(1, 0, 0, 1); STAGE(1, 1, 1, 1);
  asm volatile("s_waitcnt vmcnt(6)" ::: "memory");
  __builtin_amdgcn_s_barrier();

  for (int t = 0; t < NT; ++t) {
    const int b = t & 1;
    const int tn1 = (t + 1 < NT) ? t + 1 : 0;
    const int tn2 = (t + 2 < NT) ? t + 2 : 0;
    bf16x8 a[4], bv[4];
    // ---- phase 1: (k0, m-half 0); stage A-k1(t+1) -> other buf ----
    LDA4(b, 0, 0); LDB4(b, 0);
    STAGE(b ^ 1, 0, 1, tn1);
    __builtin_amdgcn_s_barrier();
    asm volatile("s_waitcnt lgkmcnt(0)" ::: "memory");
    __builtin_amdgcn_s_setprio(1);
    MFMA16(0);
    __builtin_amdgcn_s_setprio(0);
    __builtin_amdgcn_s_barrier();
    // ---- phase 2: (k0, m-half 1); stage B-k0(t+2) ----
    LDA4(b, 0, 1);
    STAGE(b, 1, 0, tn2);
    __builtin_amdgcn_s_barrier();
    asm volatile("s_waitcnt lgkmcnt(0)" ::: "memory");
    __builtin_amdgcn_s_setprio(1);
    MFMA16(1);
    __builtin_amdgcn_s_setprio(0);
    __builtin_amdgcn_s_barrier();
    // ---- phase 3: (k1, m-half 0); stage A-k0(t+2) ----
    LDA4(b, 1, 0); LDB4(b, 1);
    STAGE(b, 0, 0, tn2);
    __builtin_amdgcn_s_barrier();
    asm volatile("s_waitcnt lgkmcnt(0)" ::: "memory");
    __builtin_amdgcn_s_setprio(1);
    MFMA16(0);
    __builtin_amdgcn_s_setprio(0);
    __builtin_amdgcn_s_barrier();
    // ---- phase 4: (k1, m-half 1); stage B-k1(t+2); counted vmcnt ----
    LDA4(b, 1, 1);
    STAGE(b, 1, 1, tn2);
    __builtin_amdgcn_s_barrier();
    asm volatile("s_waitcnt lgkmcnt(0)" ::: "memory");
    __builtin_amdgcn_s_setprio(1);
    MFMA16(1);
    __builtin_amdgcn_s_setprio(0);
    asm volatile("s_waitcnt vmcnt(6)" ::: "memory");
    __builtin_amdgcn_s_barrier();
  }
  asm volatile("s_waitcnt vmcnt(0)" ::: "memory");

#pragma unroll
  for (int mm = 0; mm < 8; ++mm) {
#pragma unroll
    for (int n = 0; n < 4; ++n) {
      int col = (int)bCol + wn * 64 + n * 16 + c;
      if (col < Nact) {
#pragma unroll
        for (int r = 0; r < 4; ++r) {
          size_t row = bRow + wm * 128 + mm * 16 + g * 4 + r;
          C[row * ldc + col] = acc[mm][n][r];
        }
      }
    }
  }
}

// fused[n][l][E_STR] f32 -> Qb [n][h][l][64] bf16 (RoPE, *0.125), Kb [n][l][64] (RoPE),
// VTb [n][64][SEQ] (transposed V, no RoPE)
__global__ void rope_extract(const float* __restrict__ fused,
                             unsigned short* __restrict__ Qb,
                             unsigned short* __restrict__ Kb,
                             unsigned short* __restrict__ VTb) {
  int idx = blockIdx.x * 256 + threadIdx.x;
  const int total = NB * SEQ * 73 * 64;
  if (idx >= total) return;
  int d = idx & 63;
  int t = idx >> 6;
  int h = t % 73;  t /= 73;
  int l = t & (SEQ - 1);
  int n = t >> 10;
  const float* frow = fused + ((size_t)(n * SEQ + l)) * E_STR + h * 64;
  float x = frow[d];
  if (h == 72) {
    VTb[((size_t)(n * 64 + d)) * SEQ + l] = f2bf(x);
    return;
  }
  int dh = d & 31;
  float inv = __expf(-(float)dh * (9.210340371976184f / 32.0f));
  float ang = (float)l * inv;
  float sn, cs;
  __sincosf(ang, &sn, &cs);
  float xr = frow[(d < 32) ? d + 32 : d - 32];
  float rh = (d < 32) ? -xr : xr;
  float out = x * cs + rh * sn;
  if (h == 71) {
    Kb[((size_t)(n * SEQ + l)) * 64 + d] = f2bf(out);
  } else {
    Qb[(((size_t)(n * NH + h)) * SEQ + l) * 64 + d] = f2bf(out * 0.125f);
  }
}

// Swapped-QK^T flash MQA (unchanged from round 2).
__global__ __launch_bounds__(128) void attn_kernel(
    const unsigned short* __restrict__ Qb,
    const unsigned short* __restrict__ Kb,
    const unsigned short* __restrict__ VTb,
    unsigned short* __restrict__ attnb) {
  const int qt = 15 - blockIdx.x;
  const int h = blockIdx.y, n = blockIdx.z;
  const int wave = threadIdx.x >> 6, lane = threadIdx.x & 63;
  const int c = lane & 31, hi = lane >> 5;
  const int qrow0 = qt * 64 + wave * 32;
  const int q = qrow0 + c;

  const unsigned short* qbase = Qb + (((size_t)(n * NH + h)) * SEQ + qrow0) * 64;
  const unsigned short* kbase = Kb + (size_t)n * SEQ * 64;
  const unsigned short* vtbase = VTb + (size_t)n * 64 * SEQ;

  bf16x8 qf[4];
#pragma unroll
  for (int cc = 0; cc < 4; ++cc)
    qf[cc] = *(const bf16x8*)&qbase[c * 64 + cc * 16 + hi * 8];

  f32x16 o0 = {}, o1 = {};
  float m_run = -1e30f, l_run = 0.f;

  for (int kt = 0; kt < qrow0 + 32; kt += 64) {
    f32x16 s0 = {}, s1 = {};
#pragma unroll
    for (int cc = 0; cc < 4; ++cc) {
      bf16x8 k0 = *(const bf16x8*)&kbase[(size_t)(kt + c) * 64 + cc * 16 + hi * 8];
      bf16x8 k1 = *(const bf16x8*)&kbase[(size_t)(kt + 32 + c) * 64 + cc * 16 + hi * 8];
      s0 = __builtin_amdgcn_mfma_f32_32x32x16_bf16(k0, qf[cc], s0, 0, 0, 0);
      s1 = __builtin_amdgcn_mfma_f32_32x32x16_bf16(k1, qf[cc], s1, 0, 0, 0);
    }
    if (kt + 63 > qrow0) {
#pragma unroll
      for (int r = 0; r < 16; ++r) {
        const int key0 = kt + (r & 3) + 8 * (r >> 2) + 4 * hi;
        s0[r] = (key0 > q) ? -1e30f : s0[r];
        s1[r] = (key0 + 32 > q) ? -1e30f : s1[r];
      }
    }
    float tt[16];
#pragma unroll
    for (int r = 0; r < 16; ++r) tt[r] = fmaxf(s0[r], s1[r]);
#pragma unroll
    for (int st = 8; st > 0; st >>= 1)
#pragma unroll
      for (int r = 0; r < 8; ++r) if (r < st) tt[r] = fmaxf(tt[r], tt[r + st]);
    float mx = fmaxf(tt[0], __shfl_xor(tt[0], 32));
    const float mnew = fmaxf(m_run, mx);
    const float aa = __expf(m_run - mnew);
#pragma unroll
    for (int r = 0; r < 16; ++r) {
      s0[r] = __expf(s0[r] - mnew);
      s1[r] = __expf(s1[r] - mnew);
    }
    float ps = 0.f;
#pragma unroll
    for (int r = 0; r < 16; ++r) ps += s0[r] + s1[r];
    ps += __shfl_xor(ps, 32);
    l_run = l_run * aa + ps;
    m_run = mnew;
#pragma unroll
    for (int r = 0; r < 16; ++r) { o0[r] *= aa; o1[r] *= aa; }

#pragma unroll
    for (int half = 0; half < 2; ++half) {
#pragma unroll
      for (int ccl = 0; ccl < 2; ++ccl) {
        const int cg = half * 2 + ccl;
        unsigned a0, a1, b0, b1;
        if (half == 0) {
          a0 = cvtpk_bf16(s0[8 * ccl + 0], s0[8 * ccl + 1]);
          a1 = cvtpk_bf16(s0[8 * ccl + 2], s0[8 * ccl + 3]);
          b0 = cvtpk_bf16(s0[8 * ccl + 4], s0[8 * ccl + 5]);
          b1 = cvtpk_bf16(s0[8 * ccl + 6], s0[8 * ccl + 7]);
        } else {
          a0 = cvtpk_bf16(s1[8 * ccl + 0], s1[8 * ccl + 1]);
          a1 = cvtpk_bf16(s1[8 * ccl + 2], s1[8 * ccl + 3]);
          b0 = cvtpk_bf16(s1[8 * ccl + 4], s1[8 * ccl + 5]);
          b1 = cvtpk_bf16(s1[8 * ccl + 6], s1[8 * ccl + 7]);
        }
        unsigned xa0 = __shfl_xor(a0, 32), xa1 = __shfl_xor(a1, 32);
        unsigned xb0 = __shfl_xor(b0, 32), xb1 = __shfl_xor(b1, 32);
        u32x4 fw;
        fw[0] = hi ? xb0 : a0;
        fw[1] = hi ? xb1 : a1;
        fw[2] = hi ? b0 : xa0;
        fw[3] = hi ? b1 : xa1;
        union { u32x4 u; bf16x8 b; } pf; pf.u = fw;
        bf16x8 v0 = *(const bf16x8*)&vtbase[(size_t)c * SEQ + kt + cg * 16 + hi * 8];
        bf16x8 v1 = *(const bf16x8*)&vtbase[(size_t)(32 + c) * SEQ + kt + cg * 16 + hi * 8];
        o0 = __builtin_amdgcn_mfma_f32_32x32x16_bf16(v0, pf.b, o0, 0, 0, 0);
        o1 = __builtin_amdgcn_mfma_f32_32x32x16_bf16(v1, pf.b, o1, 0, 0, 0);
      }
    }
  }

  const float inv = 1.0f / l_run;
  const size_t rowoff = (size_t)(n * SEQ + q) * D_MODEL + h * 64;
#pragma unroll
  for (int rr = 0; rr < 4; ++rr) {
    ushort4 w0, w1;
    w0.x = f2bf(o0[4 * rr + 0] * inv); w0.y = f2bf(o0[4 * rr + 1] * inv);
    w0.z = f2bf(o0[4 * rr + 2] * inv); w0.w = f2bf(o0[4 * rr + 3] * inv);
    w1.x = f2bf(o1[4 * rr + 0] * inv); w1.y = f2bf(o1[4 * rr + 1] * inv);
    w1.z = f2bf(o1[4 * rr + 2] * inv); w1.w = f2bf(o1[4 * rr + 3] * inv);
    *(ushort4*)&attnb[rowoff + 8 * rr + 4 * hi] = w0;
    *(ushort4*)&attnb[rowoff + 32 + 8 * rr + 4 * hi] = w1;
  }
}

extern "C" void kernel_launch(void* const* d_in, const int* in_sizes, int n_in,
                              void* d_out, int out_size, void* d_ws, size_t ws_size,
                              hipStream_t stream) {
  const float* hs = (const float*)d_in[0];
  const float* wqkv = (const float*)d_in[1];
  const float* wdense = (const float*)d_in[2];
  float* out = (float*)d_out;
  char* ws = (char*)d_ws;

  // ws layout (bytes)
  unsigned short* hsb   = (unsigned short*)(ws + 0);            // 18,612,224
  unsigned short* wqkvb = (unsigned short*)(ws + 18612224);     // 4864*4544*2 = 44,208,128
  unsigned short* wdb   = (unsigned short*)(ws + 62820352);     // 4608*4544*2 = 41,881,600
  float*          fused = (float*)(ws + 104701952);             // 2048*4736*4 = 38,797,312
  unsigned short* qb    = (unsigned short*)(ws + 143499264);    // 18,612,224
  unsigned short* kb    = (unsigned short*)(ws + 162111488);    // 262,144
  unsigned short* vtb   = (unsigned short*)(ws + 162373632);    // 262,144
  unsigned short* attnb = (unsigned short*)(ws + 162635776);    // 18,612,224
  // total: 181,248,000

  {
    int total = M_ROWS * (D_MODEL / 4);
    convert_pad<<<(total + 255) / 256, 256, 0, stream>>>(hs, hsb, M_ROWS, M_ROWS, D_MODEL);
  }
  {
    int total = E_PAD2 * (D_MODEL / 4);
    convert_pad<<<(total + 255) / 256, 256, 0, stream>>>(wqkv, wqkvb, E_QKV, E_PAD2, D_MODEL);
  }
  {
    int total = D_PAD * (D_MODEL / 4);
    convert_pad<<<(total + 255) / 256, 256, 0, stream>>>(wdense, wdb, D_MODEL, D_PAD, D_MODEL);
  }
  gemm256<<<dim3(8 * 19), 512, 0, stream>>>(hsb, wqkvb, fused, D_MODEL, 19, E_STR, E_STR);
  {
    int total = NB * SEQ * 73 * 64;
    rope_extract<<<(total + 255) / 256, 256, 0, stream>>>(fused, qb, kb, vtb);
  }
  attn_kernel<<<dim3(16, NH, NB), 128, 0, stream>>>(qb, kb, vtb, attnb);
  gemm256<<<dim3(8 * 18), 512, 0, stream>>>(attnb, wdb, out, D_MODEL, 18, D_MODEL, D_MODEL);
}

// Round 4
// 432.553 us; speedup vs baseline: 1.6763x; 1.1195x over previous
//
#include <hip/hip_runtime.h>

#define D_MODEL 4544
#define E_QKV   4672     // D + 2*64
#define E_STR   4736     // fused row stride (37*128)
#define E_PAD2  4864     // QKV weight rows padded (19*256)
#define D_PAD   4608     // dense weight rows padded (18*256)
#define NH      71
#define SEQ     1024
#define NB      2
#define M_ROWS  2048     // NB*SEQ

typedef __bf16 bf16_t;
typedef bf16_t bf16x8 __attribute__((ext_vector_type(8)));
typedef float f32x4 __attribute__((ext_vector_type(4)));
typedef float f32x16 __attribute__((ext_vector_type(16)));
typedef unsigned u32x4 __attribute__((ext_vector_type(4)));

typedef __attribute__((address_space(1))) const void* gas_ptr;
typedef __attribute__((address_space(3))) void* las_ptr;

static __device__ __forceinline__ unsigned short f2bf(float f) {
  union { float f; unsigned u; } v; v.f = f;
  unsigned r = (v.u + 0x7fffu + ((v.u >> 16) & 1u)) >> 16;
  return (unsigned short)r;
}

static __device__ __forceinline__ unsigned cvtpk_bf16(float lo, float hi) {
  unsigned r;
  asm("v_cvt_pk_bf16_f32 %0, %1, %2" : "=v"(r) : "v"(lo), "v"(hi));
  return r;
}

static __device__ __forceinline__ float fast_exp2(float x) {
  float r;
  asm("v_exp_f32 %0, %1" : "=v"(r) : "v"(x));
  return r;
}

// dst[rows_pad][cols] bf16 <- src[rows_src][cols] f32, pad rows zeroed.
__global__ void convert_pad(const float* __restrict__ src, unsigned short* __restrict__ dst,
                            int rows_src, int rows_pad, int cols) {
  int idx = blockIdx.x * 256 + threadIdx.x;
  int cols4 = cols >> 2;
  int total = rows_pad * cols4;
  if (idx >= total) return;
  int row = idx / cols4;
  int c4 = (idx - row * cols4) << 2;
  ushort4 o;
  if (row < rows_src) {
    const float4 v = *(const float4*)(src + (size_t)row * cols + c4);
    o.x = f2bf(v.x); o.y = f2bf(v.y); o.z = f2bf(v.z); o.w = f2bf(v.w);
  } else {
    o.x = 0; o.y = 0; o.z = 0; o.w = 0;
  }
  *(ushort4*)(dst + (size_t)row * cols + c4) = o;
}

// ---------------- 256x256 8-phase GEMM (C = A * B^T) ----------------
#define REGION(b_, op_, kh_) (((((b_)*2+(op_))*2)+(kh_)) << 13)

#define STAGE(b_, op_, kh_, kt_) do {                                          \
  const unsigned short* _src = (op_) ? B : A;                                  \
  const size_t _rb = (op_) ? bCol : bRow;                                      \
  _Pragma("unroll")                                                            \
  for (int _ld = 0; _ld < 2; ++_ld) {                                          \
    int _ch = _ld * 512 + tid;                                                 \
    const unsigned short* _ga = _src + (_rb + (_ch >> 2)) * K                  \
                                + (kt_) * 64 + (kh_) * 32 + ((_ch & 3) << 3);  \
    __builtin_amdgcn_global_load_lds((gas_ptr)_ga,                             \
        (las_ptr)(lds + REGION(b_, op_, kh_) + ((_ld * 512 + wave * 64) << 3)),\
        16, 0, 0);                                                             \
  }                                                                            \
} while (0)

#define LDA4(b_, kh_, mh_) do {                                                \
  const unsigned short* _ab = lds + REGION(b_, 0, kh_);                        \
  _Pragma("unroll")                                                            \
  for (int _mm = 0; _mm < 4; ++_mm)                                            \
    a[_mm] = *(const bf16x8*)&_ab[(wm * 128 + (mh_) * 64 + _mm * 16 + c) * 32 + g * 8]; \
} while (0)

#define LDB4(b_, kh_) do {                                                     \
  const unsigned short* _bp = lds + REGION(b_, 1, kh_);                        \
  _Pragma("unroll")                                                            \
  for (int _n = 0; _n < 4; ++_n)                                               \
    bv[_n] = *(const bf16x8*)&_bp[(wn * 64 + _n * 16 + c) * 32 + g * 8];       \
} while (0)

#define MFMA16(mh_) do {                                                       \
  _Pragma("unroll")                                                            \
  for (int _mm = 0; _mm < 4; ++_mm)                                            \
    _Pragma("unroll")                                                          \
    for (int _n = 0; _n < 4; ++_n)                                             \
      acc[(mh_) * 4 + _mm][_n] = __builtin_amdgcn_mfma_f32_16x16x32_bf16(      \
          a[_mm], bv[_n], acc[(mh_) * 4 + _mm][_n], 0, 0, 0);                  \
} while (0)

__global__ __launch_bounds__(512, 2) void gemm256(
    const unsigned short* __restrict__ A,
    const unsigned short* __restrict__ B,
    float* __restrict__ C,
    int K, int Ntiles, int ldc, int Nact) {
  __shared__ __align__(16) unsigned short lds[65536];   // 128 KiB
  const int tid = threadIdx.x;
  const int wave = tid >> 6, lane = tid & 63;
  const int g = lane >> 4, c = lane & 15;
  const int wm = wave >> 2, wn = wave & 3;
  const int nwg = gridDim.x;
  const int swz = (blockIdx.x & 7) * (nwg >> 3) + (blockIdx.x >> 3);
  const int bm = swz / Ntiles, bn = swz - bm * Ntiles;
  const size_t bRow = (size_t)bm * 256, bCol = (size_t)bn * 256;
  const int NT = K >> 6;

  f32x4 acc[8][4] = {};

  STAGE(0, 0, 0, 0); STAGE(0, 1, 0, 0); STAGE(0, 0, 1, 0); STAGE(0, 1, 1, 0);
  STAGE(1, 1, 0, 1); STAGE(1, 0, 0, 1); STAGE(1, 1, 1, 1);
  asm volatile("s_waitcnt vmcnt(6)" ::: "memory");
  __builtin_amdgcn_s_barrier();

  for (int t = 0; t < NT; ++t) {
    const int b = t & 1;
    const int tn1 = (t + 1 < NT) ? t + 1 : 0;
    const int tn2 = (t + 2 < NT) ? t + 2 : 0;
    bf16x8 a[4], bv[4];
    LDA4(b, 0, 0); LDB4(b, 0);
    STAGE(b ^ 1, 0, 1, tn1);
    __builtin_amdgcn_s_barrier();
    asm volatile("s_waitcnt lgkmcnt(0)" ::: "memory");
    __builtin_amdgcn_s_setprio(1);
    MFMA16(0);
    __builtin_amdgcn_s_setprio(0);
    __builtin_amdgcn_s_barrier();
    LDA4(b, 0, 1);
    STAGE(b, 1, 0, tn2);
    __builtin_amdgcn_s_barrier();
    asm volatile("s_waitcnt lgkmcnt(0)" ::: "memory");
    __builtin_amdgcn_s_setprio(1);
    MFMA16(1);
    __builtin_amdgcn_s_setprio(0);
    __builtin_amdgcn_s_barrier();
    LDA4(b, 1, 0); LDB4(b, 1);
    STAGE(b, 0, 0, tn2);
    __builtin_amdgcn_s_barrier();
    asm volatile("s_waitcnt lgkmcnt(0)" ::: "memory");
    __builtin_amdgcn_s_setprio(1);
    MFMA16(0);
    __builtin_amdgcn_s_setprio(0);
    __builtin_amdgcn_s_barrier();
    LDA4(b, 1, 1);
    STAGE(b, 1, 1, tn2);
    __builtin_amdgcn_s_barrier();
    asm volatile("s_waitcnt lgkmcnt(0)" ::: "memory");
    __builtin_amdgcn_s_setprio(1);
    MFMA16(1);
    __builtin_amdgcn_s_setprio(0);
    asm volatile("s_waitcnt vmcnt(6)" ::: "memory");
    __builtin_amdgcn_s_barrier();
  }
  asm volatile("s_waitcnt vmcnt(0)" ::: "memory");

#pragma unroll
  for (int mm = 0; mm < 8; ++mm) {
#pragma unroll
    for (int n = 0; n < 4; ++n) {
      int col = (int)bCol + wn * 64 + n * 16 + c;
      if (col < Nact) {
#pragma unroll
        for (int r = 0; r < 4; ++r) {
          size_t row = bRow + wm * 128 + mm * 16 + g * 4 + r;
          C[row * ldc + col] = acc[mm][n][r];
        }
      }
    }
  }
}

// fused[n][l][E_STR] f32 -> Qb (RoPE, *0.125*log2e), Kb (RoPE), VTb (V^T)
__global__ void rope_extract(const float* __restrict__ fused,
                             unsigned short* __restrict__ Qb,
                             unsigned short* __restrict__ Kb,
                             unsigned short* __restrict__ VTb) {
  int idx = blockIdx.x * 256 + threadIdx.x;
  const int total = NB * SEQ * 73 * 64;
  if (idx >= total) return;
  int d = idx & 63;
  int t = idx >> 6;
  int h = t % 73;  t /= 73;
  int l = t & (SEQ - 1);
  int n = t >> 10;
  const float* frow = fused + ((size_t)(n * SEQ + l)) * E_STR + h * 64;
  float x = frow[d];
  if (h == 72) {
    VTb[((size_t)(n * 64 + d)) * SEQ + l] = f2bf(x);
    return;
  }
  int dh = d & 31;
  float inv = __expf(-(float)dh * (9.210340371976184f / 32.0f));
  float ang = (float)l * inv;
  float sn, cs;
  __sincosf(ang, &sn, &cs);
  float xr = frow[(d < 32) ? d + 32 : d - 32];
  float rh = (d < 32) ? -xr : xr;
  float out = x * cs + rh * sn;
  if (h == 71) {
    Kb[((size_t)(n * SEQ + l)) * 64 + d] = f2bf(out);
  } else {
    // fold softmax scale (1/8) and log2(e) for base-2 softmax
    Qb[(((size_t)(n * NH + h)) * SEQ + l) * 64 + d] = f2bf(out * 0.1803368801111204f);
  }
}

// Swapped-QK^T flash MQA with per-wave causal pairing: wave gw handles 32-row
// q-tiles (31-gw) then (gw) -> every wave does ~17 k-iterations (no tail).
__global__ __launch_bounds__(128) void attn_kernel(
    const unsigned short* __restrict__ Qb,
    const unsigned short* __restrict__ Kb,
    const unsigned short* __restrict__ VTb,
    unsigned short* __restrict__ attnb) {
  const int h = blockIdx.y, n = blockIdx.z;
  const int wave = threadIdx.x >> 6, lane = threadIdx.x & 63;
  const int c = lane & 31, hi = lane >> 5;
  const int gw = blockIdx.x * 2 + wave;   // 0..15

  const unsigned short* kbase = Kb + (size_t)n * SEQ * 64;
  const unsigned short* vtbase = VTb + (size_t)n * 64 * SEQ;

  for (int pass = 0; pass < 2; ++pass) {
    const int tile = pass ? gw : (31 - gw);
    const int qrow0 = tile * 32;
    const int q = qrow0 + c;
    const unsigned short* qbase = Qb + (((size_t)(n * NH + h)) * SEQ + qrow0) * 64;

    bf16x8 qf[4];
#pragma unroll
    for (int cc = 0; cc < 4; ++cc)
      qf[cc] = *(const bf16x8*)&qbase[c * 64 + cc * 16 + hi * 8];

    f32x16 o0 = {}, o1 = {};
    float m_run = -1e30f, l_run = 0.f;

    for (int kt = 0; kt < qrow0 + 32; kt += 64) {
      f32x16 s0 = {}, s1 = {};
#pragma unroll
      for (int cc = 0; cc < 4; ++cc) {
        bf16x8 k0 = *(const bf16x8*)&kbase[(size_t)(kt + c) * 64 + cc * 16 + hi * 8];
        bf16x8 k1 = *(const bf16x8*)&kbase[(size_t)(kt + 32 + c) * 64 + cc * 16 + hi * 8];
        s0 = __builtin_amdgcn_mfma_f32_32x32x16_bf16(k0, qf[cc], s0, 0, 0, 0);
        s1 = __builtin_amdgcn_mfma_f32_32x32x16_bf16(k1, qf[cc], s1, 0, 0, 0);
      }
      if (kt + 63 > qrow0) {
#pragma unroll
        for (int r = 0; r < 16; ++r) {
          const int key0 = kt + (r & 3) + 8 * (r >> 2) + 4 * hi;
          s0[r] = (key0 > q) ? -1e30f : s0[r];
          s1[r] = (key0 + 32 > q) ? -1e30f : s1[r];
        }
      }
      float tt[16];
#pragma unroll
      for (int r = 0; r < 16; ++r) tt[r] = fmaxf(s0[r], s1[r]);
#pragma unroll
      for (int st = 8; st > 0; st >>= 1)
#pragma unroll
        for (int r = 0; r < 8; ++r) if (r < st) tt[r] = fmaxf(tt[r], tt[r + st]);
      float mx = fmaxf(tt[0], __shfl_xor(tt[0], 32));
      const float mnew = fmaxf(m_run, mx);
      const float aa = fast_exp2(m_run - mnew);
#pragma unroll
      for (int r = 0; r < 16; ++r) {
        s0[r] = fast_exp2(s0[r] - mnew);
        s1[r] = fast_exp2(s1[r] - mnew);
      }
      float ps = 0.f;
#pragma unroll
      for (int r = 0; r < 16; ++r) ps += s0[r] + s1[r];
      ps += __shfl_xor(ps, 32);
      l_run = l_run * aa + ps;
      m_run = mnew;
#pragma unroll
      for (int r = 0; r < 16; ++r) { o0[r] *= aa; o1[r] *= aa; }

#pragma unroll
      for (int half = 0; half < 2; ++half) {
#pragma unroll
        for (int ccl = 0; ccl < 2; ++ccl) {
          const int cg = half * 2 + ccl;
          unsigned a0, a1, b0, b1;
          if (half == 0) {
            a0 = cvtpk_bf16(s0[8 * ccl + 0], s0[8 * ccl + 1]);
            a1 = cvtpk_bf16(s0[8 * ccl + 2], s0[8 * ccl + 3]);
            b0 = cvtpk_bf16(s0[8 * ccl + 4], s0[8 * ccl + 5]);
            b1 = cvtpk_bf16(s0[8 * ccl + 6], s0[8 * ccl + 7]);
          } else {
            a0 = cvtpk_bf16(s1[8 * ccl + 0], s1[8 * ccl + 1]);
            a1 = cvtpk_bf16(s1[8 * ccl + 2], s1[8 * ccl + 3]);
            b0 = cvtpk_bf16(s1[8 * ccl + 4], s1[8 * ccl + 5]);
            b1 = cvtpk_bf16(s1[8 * ccl + 6], s1[8 * ccl + 7]);
          }
          unsigned xa0 = __shfl_xor(a0, 32), xa1 = __shfl_xor(a1, 32);
          unsigned xb0 = __shfl_xor(b0, 32), xb1 = __shfl_xor(b1, 32);
          u32x4 fw;
          fw[0] = hi ? xb0 : a0;
          fw[1] = hi ? xb1 : a1;
          fw[2] = hi ? b0 : xa0;
          fw[3] = hi ? b1 : xa1;
          union { u32x4 u; bf16x8 b; } pf; pf.u = fw;
          bf16x8 v0 = *(const bf16x8*)&vtbase[(size_t)c * SEQ + kt + cg * 16 + hi * 8];
          bf16x8 v1 = *(const bf16x8*)&vtbase[(size_t)(32 + c) * SEQ + kt + cg * 16 + hi * 8];
          o0 = __builtin_amdgcn_mfma_f32_32x32x16_bf16(v0, pf.b, o0, 0, 0, 0);
          o1 = __builtin_amdgcn_mfma_f32_32x32x16_bf16(v1, pf.b, o1, 0, 0, 0);
        }
      }
    }

    const float inv = 1.0f / l_run;
    const size_t rowoff = (size_t)(n * SEQ + q) * D_MODEL + h * 64;
#pragma unroll
    for (int rr = 0; rr < 4; ++rr) {
      ushort4 w0, w1;
      w0.x = f2bf(o0[4 * rr + 0] * inv); w0.y = f2bf(o0[4 * rr + 1] * inv);
      w0.z = f2bf(o0[4 * rr + 2] * inv); w0.w = f2bf(o0[4 * rr + 3] * inv);
      w1.x = f2bf(o1[4 * rr + 0] * inv); w1.y = f2bf(o1[4 * rr + 1] * inv);
      w1.z = f2bf(o1[4 * rr + 2] * inv); w1.w = f2bf(o1[4 * rr + 3] * inv);
      *(ushort4*)&attnb[rowoff + 8 * rr + 4 * hi] = w0;
      *(ushort4*)&attnb[rowoff + 32 + 8 * rr + 4 * hi] = w1;
    }
  }
}

extern "C" void kernel_launch(void* const* d_in, const int* in_sizes, int n_in,
                              void* d_out, int out_size, void* d_ws, size_t ws_size,
                              hipStream_t stream) {
  const float* hs = (const float*)d_in[0];
  const float* wqkv = (const float*)d_in[1];
  const float* wdense = (const float*)d_in[2];
  float* out = (float*)d_out;
  char* ws = (char*)d_ws;

  unsigned short* hsb   = (unsigned short*)(ws + 0);            // 18,612,224
  unsigned short* wqkvb = (unsigned short*)(ws + 18612224);     // 44,208,128
  unsigned short* wdb   = (unsigned short*)(ws + 62820352);     // 41,881,600
  float*          fused = (float*)(ws + 104701952);             // 38,797,312
  unsigned short* qb    = (unsigned short*)(ws + 143499264);    // 18,612,224
  unsigned short* kb    = (unsigned short*)(ws + 162111488);    // 262,144
  unsigned short* vtb   = (unsigned short*)(ws + 162373632);    // 262,144
  unsigned short* attnb = (unsigned short*)(ws + 162635776);    // 18,612,224

  {
    int total = M_ROWS * (D_MODEL / 4);
    convert_pad<<<(total + 255) / 256, 256, 0, stream>>>(hs, hsb, M_ROWS, M_ROWS, D_MODEL);
  }
  {
    int total = E_PAD2 * (D_MODEL / 4);
    convert_pad<<<(total + 255) / 256, 256, 0, stream>>>(wqkv, wqkvb, E_QKV, E_PAD2, D_MODEL);
  }
  {
    int total = D_PAD * (D_MODEL / 4);
    convert_pad<<<(total + 255) / 256, 256, 0, stream>>>(wdense, wdb, D_MODEL, D_PAD, D_MODEL);
  }
  gemm256<<<dim3(8 * 19), 512, 0, stream>>>(hsb, wqkvb, fused, D_MODEL, 19, E_STR, E_STR);
  {
    int total = NB * SEQ * 73 * 64;
    rope_extract<<<(total + 255) / 256, 256, 0, stream>>>(fused, qb, kb, vtb);
  }
  attn_kernel<<<dim3(8, NH, NB), 128, 0, stream>>>(qb, kb, vtb, attnb);
  gemm256<<<dim3(8 * 18), 512, 0, stream>>>(attnb, wdb, out, D_MODEL, 18, D_MODEL, D_MODEL);
}